// Round 13
// baseline (672.850 us; speedup 1.0000x reference)
//
#include <hip/hip_runtime.h>

#define NN 50000
#define NE 800000
#define DD 64
#define NL 5
#define NG 256
#define NC 10
#define BN_EPS 1e-5f
#define NCHUNK ((NN + 255) / 256)   // 196
#define GROWS 128                    // rows per gemm block
#define GT (GROWS / 16)              // 16-row tiles per block
#define SAW 68                       // layer-0 staged-A row stride (uints)
#define SXW 36                       // bf16 staged-A row stride (uints): 144 B, 16B-aligned
#define GEMM_BLOCKS ((NN + GROWS - 1) / GROWS)   // 391

typedef __attribute__((ext_vector_type(8))) short bf16x8;
typedef __attribute__((ext_vector_type(4))) float f32x4;

__device__ inline float bf2f(unsigned short u) {
    return __uint_as_float((unsigned)u << 16);
}
__device__ inline unsigned short f2bf(float x) {   // RNE
    unsigned u = __float_as_uint(x);
    u += 0x7FFFu + ((u >> 16) & 1u);
    return (unsigned short)(u >> 16);
}

// Pack two floats as bf16 (RNE) into one uint: low16 = q, high16 = v.
__device__ inline unsigned int pack_bf16x2(float q, float v) {
    unsigned int uq = __float_as_uint(q);
    unsigned int uv = __float_as_uint(v);
    uq += 0x7FFFu + ((uq >> 16) & 1u);
    uv += 0x7FFFu + ((uv >> 16) & 1u);
    return (uv & 0xFFFF0000u) | (uq >> 16);
}

// Split fp32 into bf16 hi (RTZ) + bf16 lo (residual). hi+lo ~ x to ~2^-17.
__device__ inline void split_bf16(float x, short& h, short& l) {
    const unsigned u  = __float_as_uint(x);
    const unsigned hb = u & 0xFFFF0000u;
    h = (short)(hb >> 16);
    const float lo = x - __uint_as_float(hb);
    l = (short)(__float_as_uint(lo) >> 16);
}

// gate-fma for one packed bf16 q|v edge value (sigmoid via v_exp + v_rcp).
__device__ inline float gate_fma(float k, unsigned p, float acc) {
    const float q = __uint_as_float(p << 16);
    const float v = __uint_as_float(p & 0xFFFF0000u);
    const float e = __expf(-(k + q));
    return fmaf(__builtin_amdgcn_rcpf(1.f + e), v, acc);
}

// ---------------------------------------------------------------------------
// Per-layer W refresh with ALGEBRAIC BN FOLD:
//   x' = a.x + b  (prev-layer BN)  =>  x'@W = x @ (diag(a)W) + b.W
// Writes split-bf16 fragments of W' = diag(a)W in MFMA read order and the
// adjusted bias badj = bias + b.W. stats==null -> identity (layer 0).
// Grid: 4 blocks (one per matrix) x 64 threads (one per output column).
// ---------------------------------------------------------------------------
__global__ __launch_bounds__(64) void wrefresh_kernel(
    const float* __restrict__ Wk, const float* __restrict__ Wq,
    const float* __restrict__ Wv, const float* __restrict__ Ws,
    const float* __restrict__ bk, const float* __restrict__ bq,
    const float* __restrict__ bv, const float* __restrict__ bs,
    const float* __restrict__ stats,   // 128 floats (sum,sumsq) or null
    const float* __restrict__ gamma, const float* __restrict__ beta,
    bf16x8* __restrict__ wh, bf16x8* __restrict__ wl,
    float* __restrict__ badj)          // 4*64
{
    __shared__ float sa[64], sb[64];
    const int col = threadIdx.x;
    const int m   = blockIdx.x;

    {   // BN affine coeffs for this thread's k index
        float a = 1.f, b = 0.f;
        if (stats) {
            const float invN = 1.0f / (float)NN;
            const float mean = stats[col] * invN;
            const float var  = stats[64 + col] * invN - mean * mean;
            const float inv  = rsqrtf(var + BN_EPS);
            a = inv * gamma[col];
            b = beta[col] - mean * a;
        }
        sa[col] = a;
        sb[col] = b;
    }
    __syncthreads();

    const float* Wm4[4] = {Wk, Wq, Wv, Ws};
    const float* bm4[4] = {bk, bq, bv, bs};
    const float* W = Wm4[m];
    unsigned short* whs = (unsigned short*)wh;
    unsigned short* wls = (unsigned short*)wl;

    float bacc = bm4[m][col];
    const int lane_lo = col & 15;
    const int w       = col >> 4;
    for (int k = 0; k < 64; k++) {
        const float wv_ = W[k * DD + col];
        bacc += sb[k] * wv_;
        short hs, ls;
        split_bf16(sa[k] * wv_, hs, ls);
        const int c  = k >> 5;
        const int kk = k & 31;
        const int g  = kk >> 3;
        const int j  = kk & 7;
        const int frag = m * 512 + c * 256 + w * 64 + (g * 16 + lane_lo);
        whs[frag * 8 + j] = (unsigned short)hs;
        wls[frag * 8 + j] = (unsigned short)ls;
    }
    badj[m * 64 + col] = bacc;
}

// ---------------------------------------------------------------------------
// Layer-0 gemm: A = fp32 X, split hi/lo (3 MFMAs per product). W' = W
// (identity fold). Outputs K(bf16), QVp(packed), H(bf16).
// ---------------------------------------------------------------------------
__global__ __launch_bounds__(256) void gemm0_mfma(
    const float* __restrict__ X,
    const bf16x8* __restrict__ whbuf, const bf16x8* __restrict__ wlbuf,
    const float* __restrict__ badj,
    unsigned short* __restrict__ Kb, unsigned int* __restrict__ QVp,
    unsigned short* __restrict__ OUTb)
{
    __shared__ unsigned int sA[GROWS * SAW];   // packed split-bf16 A
    const int tid = threadIdx.x;

    const int row0 = blockIdx.x * GROWS;
    for (int i = tid; i < GROWS * 16; i += 256) {
        const int row = i >> 4;
        const int k4  = (i & 15) * 4;
        float4 x = make_float4(0.f, 0.f, 0.f, 0.f);
        if (row0 + row < NN)
            x = *(const float4*)(X + (size_t)(row0 + row) * DD + k4);
        const float xs[4] = {x.x, x.y, x.z, x.w};
        unsigned int* dst = &sA[row * SAW + k4];
#pragma unroll
        for (int j = 0; j < 4; j++) {
            short hs, ls;
            split_bf16(xs[j], hs, ls);
            dst[j] = ((unsigned int)(unsigned short)hs << 16) | (unsigned short)ls;
        }
    }

    const int wave = tid >> 6;
    const int lane = tid & 63;
    const int n15  = lane & 15;
    const int g    = lane >> 4;
    const int col  = wave * 16 + n15;

    bf16x8 wh[4][2], wl[4][2];
    {
        const int base = wave * 64 + lane;
#pragma unroll
        for (int m = 0; m < 4; m++)
#pragma unroll
            for (int c = 0; c < 2; c++) {
                const int idx = m * 512 + c * 256 + base;
                wh[m][c] = whbuf[idx];
                wl[m][c] = wlbuf[idx];
            }
    }

    const float bkc = badj[col], bqc = badj[64 + col];
    const float bvc = badj[128 + col], bsc = badj[192 + col];
    __syncthreads();

#pragma unroll 1
    for (int t = 0; t < GT; t++) {
        const int rowbase = row0 + t * 16;
        if (rowbase >= NN) break;

        bf16x8 ah[2], al[2];
#pragma unroll
        for (int c = 0; c < 2; c++) {
            const uint4 u0 = *(const uint4*)&sA[(t * 16 + n15) * SAW + g * 8 + 32 * c];
            const uint4 u1 = *(const uint4*)&sA[(t * 16 + n15) * SAW + g * 8 + 32 * c + 4];
            const unsigned int us[8] = {u0.x, u0.y, u0.z, u0.w, u1.x, u1.y, u1.z, u1.w};
            bf16x8 h, l;
#pragma unroll
            for (int j = 0; j < 8; j++) {
                h[j] = (short)(us[j] >> 16);
                l[j] = (short)(us[j] & 0xFFFFu);
            }
            ah[c] = h; al[c] = l;
        }

        f32x4 acc[4];
#pragma unroll
        for (int m = 0; m < 4; m++) acc[m] = (f32x4){0.f, 0.f, 0.f, 0.f};

#pragma unroll
        for (int c = 0; c < 2; c++) {
#pragma unroll
            for (int m = 0; m < 4; m++) {
                acc[m] = __builtin_amdgcn_mfma_f32_16x16x32_bf16(ah[c], wh[m][c], acc[m], 0, 0, 0);
                acc[m] = __builtin_amdgcn_mfma_f32_16x16x32_bf16(al[c], wh[m][c], acc[m], 0, 0, 0);
                acc[m] = __builtin_amdgcn_mfma_f32_16x16x32_bf16(ah[c], wl[m][c], acc[m], 0, 0, 0);
            }
        }

#pragma unroll
        for (int r = 0; r < 4; r++) {
            const int row = rowbase + g * 4 + r;
            const size_t o = (size_t)row * DD + col;
            Kb[o]   = f2bf(acc[0][r] + bkc);
            QVp[o]  = pack_bf16x2(acc[1][r] + bqc, acc[2][r] + bvc);
            OUTb[o] = f2bf(acc[3][r] + bsc);
        }
    }
}

// ---------------------------------------------------------------------------
// Layers 1-4 gemm: A = raw bf16 H (EXACT, BN folded into W') -> no split,
// 2 MFMAs per product (16 per tile vs 24). LDS = plain bf16 rows, stride
// SXW=36 uints (16B-aligned rows, 2-way-free bank pattern).
// ---------------------------------------------------------------------------
__global__ __launch_bounds__(256) void gemmb_mfma(
    const unsigned short* __restrict__ Hin,
    const bf16x8* __restrict__ whbuf, const bf16x8* __restrict__ wlbuf,
    const float* __restrict__ badj,
    unsigned short* __restrict__ Kb, unsigned int* __restrict__ QVp,
    unsigned short* __restrict__ OUTb)
{
    __shared__ unsigned int sX[GROWS * SXW];   // 18.4 KB bf16 rows
    const int tid = threadIdx.x;

    const int row0 = blockIdx.x * GROWS;
    for (int i = tid; i < GROWS * 8; i += 256) {   // uint4 units: 8 per row
        const int row = i >> 3;
        const int q   = i & 7;
        uint4 v = make_uint4(0u, 0u, 0u, 0u);
        if (row0 + row < NN)
            v = *(const uint4*)(Hin + (size_t)(row0 + row) * DD + q * 8);
        *(uint4*)&sX[row * SXW + q * 4] = v;
    }

    const int wave = tid >> 6;
    const int lane = tid & 63;
    const int n15  = lane & 15;
    const int g    = lane >> 4;
    const int col  = wave * 16 + n15;

    bf16x8 wh[4][2], wl[4][2];
    {
        const int base = wave * 64 + lane;
#pragma unroll
        for (int m = 0; m < 4; m++)
#pragma unroll
            for (int c = 0; c < 2; c++) {
                const int idx = m * 512 + c * 256 + base;
                wh[m][c] = whbuf[idx];
                wl[m][c] = wlbuf[idx];
            }
    }

    const float bkc = badj[col], bqc = badj[64 + col];
    const float bvc = badj[128 + col], bsc = badj[192 + col];
    __syncthreads();

#pragma unroll 1
    for (int t = 0; t < GT; t++) {
        const int rowbase = row0 + t * 16;
        if (rowbase >= NN) break;

        bf16x8 ah[2];
#pragma unroll
        for (int c = 0; c < 2; c++)
            ah[c] = *(const bf16x8*)&sX[(t * 16 + n15) * SXW + g * 4 + 16 * c];

        f32x4 acc[4];
#pragma unroll
        for (int m = 0; m < 4; m++) acc[m] = (f32x4){0.f, 0.f, 0.f, 0.f};

#pragma unroll
        for (int c = 0; c < 2; c++) {
#pragma unroll
            for (int m = 0; m < 4; m++) {
                acc[m] = __builtin_amdgcn_mfma_f32_16x16x32_bf16(ah[c], wh[m][c], acc[m], 0, 0, 0);
                acc[m] = __builtin_amdgcn_mfma_f32_16x16x32_bf16(ah[c], wl[m][c], acc[m], 0, 0, 0);
            }
        }

#pragma unroll
        for (int r = 0; r < 4; r++) {
            const int row = rowbase + g * 4 + r;
            const size_t o = (size_t)row * DD + col;
            Kb[o]   = f2bf(acc[0][r] + bkc);
            QVp[o]  = pack_bf16x2(acc[1][r] + bqc, acc[2][r] + bvc);
            OUTb[o] = f2bf(acc[3][r] + bsc);
        }
    }
}

// ---------------------------------------------------------------------------
// CSR build: histogram of dst, two-level exclusive scan, scatter fill.
// ---------------------------------------------------------------------------
__global__ __launch_bounds__(256) void deg_kernel(
    const int* __restrict__ ei, int* __restrict__ deg)
{
    const int e = blockIdx.x * 256 + threadIdx.x;
    if (e < NE) atomicAdd(&deg[ei[NE + e]], 1);
}

__global__ __launch_bounds__(256) void scan_partial_kernel(
    const int* __restrict__ deg, int* __restrict__ psums)
{
    __shared__ int ls[256];
    const int i = blockIdx.x * 256 + threadIdx.x;
    ls[threadIdx.x] = (i < NN) ? deg[i] : 0;
    __syncthreads();
    for (int off = 128; off > 0; off >>= 1) {
        if (threadIdx.x < off) ls[threadIdx.x] += ls[threadIdx.x + off];
        __syncthreads();
    }
    if (threadIdx.x == 0) psums[blockIdx.x] = ls[0];
}

__global__ void scan_offsets_kernel(int* __restrict__ psums, int* __restrict__ rowst)
{
    if (threadIdx.x == 0) {
        int running = 0;
        for (int i = 0; i < NCHUNK; i++) {
            int t = psums[i];
            psums[i] = running;
            running += t;
        }
        rowst[NN] = running;  // == NE
    }
}

__global__ __launch_bounds__(256) void scan_final_kernel(
    const int* __restrict__ deg, const int* __restrict__ psums,
    int* __restrict__ rowst, int* __restrict__ cursor)
{
    __shared__ int ls[256];
    const int i = blockIdx.x * 256 + threadIdx.x;
    const int x = (i < NN) ? deg[i] : 0;
    ls[threadIdx.x] = x;
    __syncthreads();
    for (int off = 1; off < 256; off <<= 1) {
        int v = (threadIdx.x >= off) ? ls[threadIdx.x - off] : 0;
        __syncthreads();
        ls[threadIdx.x] += v;
        __syncthreads();
    }
    if (i < NN) {
        const int excl = psums[blockIdx.x] + ls[threadIdx.x] - x;
        rowst[i]  = excl;
        cursor[i] = excl;
    }
}

__global__ __launch_bounds__(256) void fill_kernel(
    const int* __restrict__ ei, int* __restrict__ cursor, int* __restrict__ csr)
{
    const int e = blockIdx.x * 256 + threadIdx.x;
    if (e < NE) {
        const int src = ei[e];
        const int dst = ei[NE + e];
        csr[atomicAdd(&cursor[dst], 1)] = src;
    }
}

// ---------------------------------------------------------------------------
// Gather (R12, XCD-aligned): block j covers a 32-row sub-window of gemm
// block g with g%8 == j%8 (same-XCD L2 reuse of K/H under round-robin
// dispatch). Unroll-4 edge loop, bf16 K/H, stats on rounded h.
// ---------------------------------------------------------------------------
#define GATHER_BLOCKS (8 * 49 * 4)   // 1568
__global__ __launch_bounds__(256) void gather_kernel(
    const int* __restrict__ rowst, const int* __restrict__ csr,
    const unsigned short* __restrict__ Kb, const unsigned int* __restrict__ QVp,
    unsigned short* Hb, float* __restrict__ stats)
{
    const int tid = threadIdx.x;
    const int c   = tid & 63;
    const int wv  = tid >> 6;

    const int j     = blockIdx.x;
    const int lane8 = j & 7;
    const int idx   = j >> 3;               // 0..195
    const int g     = lane8 + 8 * (idx >> 2);
    const int sub   = idx & 3;
    const int base  = g * GROWS + sub * 32;

    float s = 0.f, s2 = 0.f;

    for (int t = 0; t < 8; t++) {
        const int n = base + wv + t * 4;
        if (n >= NN) break;
        const unsigned rowoff = (unsigned)(n * DD + c);
        const float k     = bf2f(Kb[rowoff]);
        const float hskip = bf2f(Hb[rowoff]);
        const int e0 = rowst[n], e1 = rowst[n + 1];
        float acc = 0.f;
        int i = e0;
        for (; i + 4 <= e1; i += 4) {
            const int s0 = csr[i], s1 = csr[i + 1], s2i = csr[i + 2], s3 = csr[i + 3];
            const unsigned p0 = QVp[(unsigned)(s0  * DD + c)];
            const unsigned p1 = QVp[(unsigned)(s1  * DD + c)];
            const unsigned p2 = QVp[(unsigned)(s2i * DD + c)];
            const unsigned p3 = QVp[(unsigned)(s3  * DD + c)];
            acc = gate_fma(k, p0, acc);
            acc = gate_fma(k, p1, acc);
            acc = gate_fma(k, p2, acc);
            acc = gate_fma(k, p3, acc);
        }
        for (; i < e1; i++) {
            const unsigned p0 = QVp[(unsigned)(csr[i] * DD + c)];
            acc = gate_fma(k, p0, acc);
        }
        const float o = fmaxf(hskip + acc, 0.f);
        const unsigned short ob = f2bf(o);
        Hb[rowoff] = ob;
        const float orr = bf2f(ob);
        s += orr;
        s2 += orr * orr;
    }

    __shared__ float ls[256], ls2[256];
    ls[tid]  = s;
    ls2[tid] = s2;
    __syncthreads();
    if (tid < 64) {
        const float a = ls[tid]  + ls[tid + 64]  + ls[tid + 128]  + ls[tid + 192];
        const float b = ls2[tid] + ls2[tid + 64] + ls2[tid + 128] + ls2[tid + 192];
        atomicAdd(&stats[c], a);
        atomicAdd(&stats[64 + c], b);
    }
}

// ---------------------------------------------------------------------------
// Pooled segment-sum over bf16 H (batch sorted -> run-length accumulate).
// ---------------------------------------------------------------------------
#define POOL_ROWS 64
__global__ __launch_bounds__(64) void pool_kernel(
    const unsigned short* __restrict__ Hb, const int* __restrict__ batch,
    float* __restrict__ psum, float* __restrict__ pcnt)
{
    const int c  = threadIdx.x;
    const int r0 = blockIdx.x * POOL_ROWS;
    if (r0 >= NN) return;
    const int r1 = min(r0 + POOL_ROWS, NN);

    int cur = batch[r0];
    float acc = 0.f, cnt = 0.f;
    for (int r = r0; r < r1; r++) {
        const int g = batch[r];
        if (g != cur) {
            atomicAdd(&psum[cur * DD + c], acc);
            if (c == 0) atomicAdd(&pcnt[cur], cnt);
            acc = 0.f; cnt = 0.f; cur = g;
        }
        acc += bf2f(Hb[(size_t)r * DD + c]);
        cnt += 1.f;
    }
    atomicAdd(&psum[cur * DD + c], acc);
    if (c == 0) atomicAdd(&pcnt[cur], cnt);
}

// ---------------------------------------------------------------------------
// Final: pooled mean -> folded last-layer BN affine -> logits -> softmax.
// ---------------------------------------------------------------------------
__global__ __launch_bounds__(256) void final_kernel(
    const float* __restrict__ psum, const float* __restrict__ pcnt,
    const float* __restrict__ stats,
    const float* __restrict__ gamma, const float* __restrict__ beta,
    const float* __restrict__ Wlin, const float* __restrict__ blin,
    float* __restrict__ out)
{
    const int g = blockIdx.x * blockDim.x + threadIdx.x;
    if (g >= NG) return;

    const float invc = 1.0f / fmaxf(pcnt[g], 1.0f);
    const float invN = 1.0f / (float)NN;
    float p[DD];
#pragma unroll
    for (int d = 0; d < DD; d++) {
        const float mean = stats[d] * invN;
        const float var  = stats[64 + d] * invN - mean * mean;
        const float inv  = rsqrtf(var + BN_EPS);
        const float a = inv * gamma[d];
        const float b = beta[d] - mean * a;
        p[d] = fmaf(psum[g * DD + d] * invc, a, b);
    }

    float logits[NC];
    float m = -1e30f;
#pragma unroll
    for (int c = 0; c < NC; c++) {
        float acc = blin[c];
#pragma unroll
        for (int d = 0; d < DD; d++) acc = fmaf(p[d], Wlin[d * NC + c], acc);
        logits[c] = acc;
        m = fmaxf(m, acc);
    }
    float sum = 0.f;
#pragma unroll
    for (int c = 0; c < NC; c++) {
        logits[c] = __expf(logits[c] - m);
        sum += logits[c];
    }
    const float inv = 1.f / sum;
#pragma unroll
    for (int c = 0; c < NC; c++) out[g * NC + c] = logits[c] * inv;
}

// ---------------------------------------------------------------------------
extern "C" void kernel_launch(void* const* d_in, const int* in_sizes, int n_in,
                              void* d_out, int out_size, void* d_ws, size_t ws_size,
                              hipStream_t stream)
{
    const float* X     = (const float*)d_in[0];
    const int*   ei    = (const int*)d_in[1];
    const int*   batch = (const int*)d_in[2];
    const float* Wk    = (const float*)d_in[3];
    const float* Wq    = (const float*)d_in[4];
    const float* Wv    = (const float*)d_in[5];
    const float* Ws    = (const float*)d_in[6];
    const float* bk    = (const float*)d_in[7];
    const float* bq    = (const float*)d_in[8];
    const float* bv    = (const float*)d_in[9];
    const float* bconv = (const float*)d_in[10];
    const float* gamma = (const float*)d_in[11];
    const float* beta  = (const float*)d_in[12];
    const float* Wlin  = (const float*)d_in[13];
    const float* blin  = (const float*)d_in[14];
    float* out = (float*)d_out;

    const size_t M = (size_t)NN * DD;
    unsigned short* Kb  = (unsigned short*)d_ws;      // M bf16
    unsigned int*   QVp = (unsigned int*)(Kb + M);    // M packed bf16 q|v
    unsigned short* H0  = (unsigned short*)(QVp + M); // M bf16
    unsigned short* H1  = H0 + M;                     // M bf16
    // --- contiguous zero-init region ---
    int*   deg   = (int*)(H1 + M);                    // NN
    float* psum  = (float*)(deg + NN);                // NG*DD
    float* pcnt  = psum + (size_t)NG * DD;            // NG
    float* stats = pcnt + NG;                         // NL*128
    // --- end zero region ---
    int* rowst  = (int*)(stats + NL * 128);           // NN+1
    int* cursor = rowst + NN + 1;                     // NN
    int* psums  = cursor + NN;                        // 256
    int* csr    = psums + 256;                        // NE
    bf16x8* whbuf = (bf16x8*)(csr + NE);              // 2048 frags (one layer)
    bf16x8* wlbuf = whbuf + 2048;                     // 2048 frags
    float*  badj  = (float*)(wlbuf + 2048);           // 4*64

    const size_t zero_bytes = (size_t)(NN + NG * DD + NG + NL * 128) * sizeof(float);
    hipMemsetAsync(deg, 0, zero_bytes, stream);

    // ---- layer-0 W fragments (identity fold) ----
    wrefresh_kernel<<<4, 64, 0, stream>>>(
        Wk, Wq, Wv, Ws, bk, bq, bv, bconv,
        nullptr, nullptr, nullptr, whbuf, wlbuf, badj);

    // ---- CSR build ----
    deg_kernel<<<(NE + 255) / 256, 256, 0, stream>>>(ei, deg);
    scan_partial_kernel<<<NCHUNK, 256, 0, stream>>>(deg, psums);
    scan_offsets_kernel<<<1, 64, 0, stream>>>(psums, rowst);
    scan_final_kernel<<<NCHUNK, 256, 0, stream>>>(deg, psums, rowst, cursor);
    fill_kernel<<<(NE + 255) / 256, 256, 0, stream>>>(ei, cursor, csr);

    // ---- layers ----
    const unsigned short* hin = nullptr;
    for (int l = 0; l < NL; l++) {
        unsigned short* hout = (l & 1) ? H1 : H0;
        if (l == 0) {
            gemm0_mfma<<<GEMM_BLOCKS, 256, 0, stream>>>(
                X, whbuf, wlbuf, badj, Kb, QVp, hout);
        } else {
            // refresh W' = diag(a)W, badj = bias + b.W for this layer
            wrefresh_kernel<<<4, 64, 0, stream>>>(
                Wk + l * 4096, Wq + l * 4096, Wv + l * 4096, Ws + l * 4096,
                bk + l * 64, bq + l * 64, bv + l * 64, bconv + l * 64,
                stats + (l - 1) * 128, gamma + (l - 1) * 64, beta + (l - 1) * 64,
                whbuf, wlbuf, badj);
            gemmb_mfma<<<GEMM_BLOCKS, 256, 0, stream>>>(
                hin, whbuf, wlbuf, badj, Kb, QVp, hout);
        }
        gather_kernel<<<GATHER_BLOCKS, 256, 0, stream>>>(
            rowst, csr, Kb, QVp, hout, stats + l * 128);
        hin = hout;
    }

    pool_kernel<<<(NN + POOL_ROWS - 1) / POOL_ROWS, 64, 0, stream>>>(
        hin, batch, psum, pcnt);
    final_kernel<<<1, 256, 0, stream>>>(
        psum, pcnt, stats + 4 * 128, gamma + 4 * 64, beta + 4 * 64, Wlin, blin, out);
}

// Round 14
// 655.602 us; speedup vs baseline: 1.0263x; 1.0263x over previous
//
#include <hip/hip_runtime.h>

#define NN 50000
#define NE 800000
#define DD 64
#define NL 5
#define NG 256
#define NC 10
#define BN_EPS 1e-5f
#define NCHUNK ((NN + 255) / 256)   // 196
#define GROWS 128                    // rows per gemm block
#define GT (GROWS / 16)              // 16-row tiles per block
#define SAW 68                       // layer-0 staged-A row stride (uints)
#define SXW 36                       // bf16 staged-A row stride (uints)
#define GEMM_BLOCKS ((NN + GROWS - 1) / GROWS)   // 391

typedef __attribute__((ext_vector_type(8))) short bf16x8;
typedef __attribute__((ext_vector_type(4))) float f32x4;

__device__ inline float bf2f(unsigned short u) {
    return __uint_as_float((unsigned)u << 16);
}
__device__ inline unsigned short f2bf(float x) {   // RNE
    unsigned u = __float_as_uint(x);
    u += 0x7FFFu + ((u >> 16) & 1u);
    return (unsigned short)(u >> 16);
}

// Pack two floats as bf16 (RNE) into one uint: low16 = q, high16 = v.
__device__ inline unsigned int pack_bf16x2(float q, float v) {
    unsigned int uq = __float_as_uint(q);
    unsigned int uv = __float_as_uint(v);
    uq += 0x7FFFu + ((uq >> 16) & 1u);
    uv += 0x7FFFu + ((uv >> 16) & 1u);
    return (uv & 0xFFFF0000u) | (uq >> 16);
}

// Split fp32 into bf16 hi (RTZ) + bf16 lo (residual). hi+lo ~ x to ~2^-17.
__device__ inline void split_bf16(float x, short& h, short& l) {
    const unsigned u  = __float_as_uint(x);
    const unsigned hb = u & 0xFFFF0000u;
    h = (short)(hb >> 16);
    const float lo = x - __uint_as_float(hb);
    l = (short)(__float_as_uint(lo) >> 16);
}

// gate-fma for one packed bf16 q|v edge value (sigmoid via v_exp + v_rcp).
__device__ inline float gate_fma(float k, unsigned p, float acc) {
    const float q = __uint_as_float(p << 16);
    const float v = __uint_as_float(p & 0xFFFF0000u);
    const float e = __expf(-(k + q));
    return fmaf(__builtin_amdgcn_rcpf(1.f + e), v, acc);
}

// ---------------------------------------------------------------------------
// Fragment-parallel W refresh with algebraic BN fold:
//   x' = a.x + b  =>  x'@W = x @ (diag(a)W) + b.W
// 2048 threads; thread t = m*512 + c*256 + w*64 + lane IS the fragment
// index. Each thread: 8 W reads, own a/b (redundant, trivial), ONE 16 B
// hi-frag + ONE 16 B lo-frag coalesced store, partial b.W via atomicAdd
// into pre-zeroed badjX (8-way contention). stats==null -> identity.
// ---------------------------------------------------------------------------
__global__ __launch_bounds__(256) void wrefresh_kernel(
    const float* __restrict__ Wk, const float* __restrict__ Wq,
    const float* __restrict__ Wv, const float* __restrict__ Ws,
    const float* __restrict__ stats,   // 128 floats (sum,sumsq) or null
    const float* __restrict__ gamma, const float* __restrict__ beta,
    bf16x8* __restrict__ wh, bf16x8* __restrict__ wl,
    float* __restrict__ badjX)         // 4*64, pre-zeroed
{
    const int t    = blockIdx.x * 256 + threadIdx.x;   // 0..2047
    const int lane = t & 63;
    const int w    = (t >> 6) & 3;
    const int c    = (t >> 8) & 1;
    const int m    = t >> 9;

    const float* Wm4[4] = {Wk, Wq, Wv, Ws};
    const float* W = Wm4[m];
    const int col = w * 16 + (lane & 15);
    const int g   = lane >> 4;
    const float invN = 1.0f / (float)NN;

    float bsum = 0.f;
    bf16x8 h, lo;
#pragma unroll
    for (int j = 0; j < 8; j++) {
        const int k = c * 32 + g * 8 + j;
        float a = 1.f, b = 0.f;
        if (stats) {
            const float mean = stats[k] * invN;
            const float var  = stats[64 + k] * invN - mean * mean;
            const float inv  = rsqrtf(var + BN_EPS);
            a = inv * gamma[k];
            b = beta[k] - mean * a;
        }
        const float wv_ = W[k * DD + col];
        bsum += b * wv_;
        short hs, ls;
        split_bf16(a * wv_, hs, ls);
        h[j] = hs; lo[j] = ls;
    }
    wh[t] = h;
    wl[t] = lo;
    atomicAdd(&badjX[m * 64 + col], bsum);
}

// ---------------------------------------------------------------------------
// Layer-0 gemm: A = fp32 X, split hi/lo (3 MFMAs per product).
// ---------------------------------------------------------------------------
__global__ __launch_bounds__(256) void gemm0_mfma(
    const float* __restrict__ X,
    const bf16x8* __restrict__ whbuf, const bf16x8* __restrict__ wlbuf,
    const float* __restrict__ bk, const float* __restrict__ bq,
    const float* __restrict__ bv, const float* __restrict__ bs,
    const float* __restrict__ badjX,
    unsigned short* __restrict__ Kb, unsigned int* __restrict__ QVp,
    unsigned short* __restrict__ OUTb)
{
    __shared__ unsigned int sA[GROWS * SAW];   // packed split-bf16 A
    const int tid = threadIdx.x;

    const int row0 = blockIdx.x * GROWS;
    for (int i = tid; i < GROWS * 16; i += 256) {
        const int row = i >> 4;
        const int k4  = (i & 15) * 4;
        float4 x = make_float4(0.f, 0.f, 0.f, 0.f);
        if (row0 + row < NN)
            x = *(const float4*)(X + (size_t)(row0 + row) * DD + k4);
        const float xs[4] = {x.x, x.y, x.z, x.w};
        unsigned int* dst = &sA[row * SAW + k4];
#pragma unroll
        for (int j = 0; j < 4; j++) {
            short hs, ls;
            split_bf16(xs[j], hs, ls);
            dst[j] = ((unsigned int)(unsigned short)hs << 16) | (unsigned short)ls;
        }
    }

    const int wave = tid >> 6;
    const int lane = tid & 63;
    const int n15  = lane & 15;
    const int g    = lane >> 4;
    const int col  = wave * 16 + n15;

    bf16x8 wh[4][2], wl[4][2];
    {
        const int base = wave * 64 + lane;
#pragma unroll
        for (int m = 0; m < 4; m++)
#pragma unroll
            for (int c = 0; c < 2; c++) {
                const int idx = m * 512 + c * 256 + base;
                wh[m][c] = whbuf[idx];
                wl[m][c] = wlbuf[idx];
            }
    }

    const float bkc = bk[col] + badjX[col];
    const float bqc = bq[col] + badjX[64 + col];
    const float bvc = bv[col] + badjX[128 + col];
    const float bsc = bs[col] + badjX[192 + col];
    __syncthreads();

#pragma unroll 1
    for (int t = 0; t < GT; t++) {
        const int rowbase = row0 + t * 16;
        if (rowbase >= NN) break;

        bf16x8 ah[2], al[2];
#pragma unroll
        for (int c = 0; c < 2; c++) {
            const uint4 u0 = *(const uint4*)&sA[(t * 16 + n15) * SAW + g * 8 + 32 * c];
            const uint4 u1 = *(const uint4*)&sA[(t * 16 + n15) * SAW + g * 8 + 32 * c + 4];
            const unsigned int us[8] = {u0.x, u0.y, u0.z, u0.w, u1.x, u1.y, u1.z, u1.w};
            bf16x8 h, l;
#pragma unroll
            for (int j = 0; j < 8; j++) {
                h[j] = (short)(us[j] >> 16);
                l[j] = (short)(us[j] & 0xFFFFu);
            }
            ah[c] = h; al[c] = l;
        }

        f32x4 acc[4];
#pragma unroll
        for (int m = 0; m < 4; m++) acc[m] = (f32x4){0.f, 0.f, 0.f, 0.f};

#pragma unroll
        for (int c = 0; c < 2; c++) {
#pragma unroll
            for (int m = 0; m < 4; m++) {
                acc[m] = __builtin_amdgcn_mfma_f32_16x16x32_bf16(ah[c], wh[m][c], acc[m], 0, 0, 0);
                acc[m] = __builtin_amdgcn_mfma_f32_16x16x32_bf16(al[c], wh[m][c], acc[m], 0, 0, 0);
                acc[m] = __builtin_amdgcn_mfma_f32_16x16x32_bf16(ah[c], wl[m][c], acc[m], 0, 0, 0);
            }
        }

#pragma unroll
        for (int r = 0; r < 4; r++) {
            const int row = rowbase + g * 4 + r;
            const size_t o = (size_t)row * DD + col;
            Kb[o]   = f2bf(acc[0][r] + bkc);
            QVp[o]  = pack_bf16x2(acc[1][r] + bqc, acc[2][r] + bvc);
            OUTb[o] = f2bf(acc[3][r] + bsc);
        }
    }
}

// ---------------------------------------------------------------------------
// Layers 1-4 gemm: A = raw bf16 H (exact, BN folded into W') -> 2 MFMAs
// per product.
// ---------------------------------------------------------------------------
__global__ __launch_bounds__(256) void gemmb_mfma(
    const unsigned short* __restrict__ Hin,
    const bf16x8* __restrict__ whbuf, const bf16x8* __restrict__ wlbuf,
    const float* __restrict__ bk, const float* __restrict__ bq,
    const float* __restrict__ bv, const float* __restrict__ bs,
    const float* __restrict__ badjX,
    unsigned short* __restrict__ Kb, unsigned int* __restrict__ QVp,
    unsigned short* __restrict__ OUTb)
{
    __shared__ unsigned int sX[GROWS * SXW];   // 18.4 KB bf16 rows
    const int tid = threadIdx.x;

    const int row0 = blockIdx.x * GROWS;
    for (int i = tid; i < GROWS * 8; i += 256) {   // uint4 units: 8 per row
        const int row = i >> 3;
        const int q   = i & 7;
        uint4 v = make_uint4(0u, 0u, 0u, 0u);
        if (row0 + row < NN)
            v = *(const uint4*)(Hin + (size_t)(row0 + row) * DD + q * 8);
        *(uint4*)&sX[row * SXW + q * 4] = v;
    }

    const int wave = tid >> 6;
    const int lane = tid & 63;
    const int n15  = lane & 15;
    const int g    = lane >> 4;
    const int col  = wave * 16 + n15;

    bf16x8 wh[4][2], wl[4][2];
    {
        const int base = wave * 64 + lane;
#pragma unroll
        for (int m = 0; m < 4; m++)
#pragma unroll
            for (int c = 0; c < 2; c++) {
                const int idx = m * 512 + c * 256 + base;
                wh[m][c] = whbuf[idx];
                wl[m][c] = wlbuf[idx];
            }
    }

    const float bkc = bk[col] + badjX[col];
    const float bqc = bq[col] + badjX[64 + col];
    const float bvc = bv[col] + badjX[128 + col];
    const float bsc = bs[col] + badjX[192 + col];
    __syncthreads();

#pragma unroll 1
    for (int t = 0; t < GT; t++) {
        const int rowbase = row0 + t * 16;
        if (rowbase >= NN) break;

        bf16x8 ah[2];
#pragma unroll
        for (int c = 0; c < 2; c++)
            ah[c] = *(const bf16x8*)&sX[(t * 16 + n15) * SXW + g * 4 + 16 * c];

        f32x4 acc[4];
#pragma unroll
        for (int m = 0; m < 4; m++) acc[m] = (f32x4){0.f, 0.f, 0.f, 0.f};

#pragma unroll
        for (int c = 0; c < 2; c++) {
#pragma unroll
            for (int m = 0; m < 4; m++) {
                acc[m] = __builtin_amdgcn_mfma_f32_16x16x32_bf16(ah[c], wh[m][c], acc[m], 0, 0, 0);
                acc[m] = __builtin_amdgcn_mfma_f32_16x16x32_bf16(ah[c], wl[m][c], acc[m], 0, 0, 0);
            }
        }

#pragma unroll
        for (int r = 0; r < 4; r++) {
            const int row = rowbase + g * 4 + r;
            const size_t o = (size_t)row * DD + col;
            Kb[o]   = f2bf(acc[0][r] + bkc);
            QVp[o]  = pack_bf16x2(acc[1][r] + bqc, acc[2][r] + bvc);
            OUTb[o] = f2bf(acc[3][r] + bsc);
        }
    }
}

// ---------------------------------------------------------------------------
// CSR build: histogram of dst, two-level exclusive scan, scatter fill.
// ---------------------------------------------------------------------------
__global__ __launch_bounds__(256) void deg_kernel(
    const int* __restrict__ ei, int* __restrict__ deg)
{
    const int e = blockIdx.x * 256 + threadIdx.x;
    if (e < NE) atomicAdd(&deg[ei[NE + e]], 1);
}

__global__ __launch_bounds__(256) void scan_partial_kernel(
    const int* __restrict__ deg, int* __restrict__ psums)
{
    __shared__ int ls[256];
    const int i = blockIdx.x * 256 + threadIdx.x;
    ls[threadIdx.x] = (i < NN) ? deg[i] : 0;
    __syncthreads();
    for (int off = 128; off > 0; off >>= 1) {
        if (threadIdx.x < off) ls[threadIdx.x] += ls[threadIdx.x + off];
        __syncthreads();
    }
    if (threadIdx.x == 0) psums[blockIdx.x] = ls[0];
}

__global__ void scan_offsets_kernel(int* __restrict__ psums, int* __restrict__ rowst)
{
    if (threadIdx.x == 0) {
        int running = 0;
        for (int i = 0; i < NCHUNK; i++) {
            int t = psums[i];
            psums[i] = running;
            running += t;
        }
        rowst[NN] = running;  // == NE
    }
}

__global__ __launch_bounds__(256) void scan_final_kernel(
    const int* __restrict__ deg, const int* __restrict__ psums,
    int* __restrict__ rowst, int* __restrict__ cursor)
{
    __shared__ int ls[256];
    const int i = blockIdx.x * 256 + threadIdx.x;
    const int x = (i < NN) ? deg[i] : 0;
    ls[threadIdx.x] = x;
    __syncthreads();
    for (int off = 1; off < 256; off <<= 1) {
        int v = (threadIdx.x >= off) ? ls[threadIdx.x - off] : 0;
        __syncthreads();
        ls[threadIdx.x] += v;
        __syncthreads();
    }
    if (i < NN) {
        const int excl = psums[blockIdx.x] + ls[threadIdx.x] - x;
        rowst[i]  = excl;
        cursor[i] = excl;
    }
}

__global__ __launch_bounds__(256) void fill_kernel(
    const int* __restrict__ ei, int* __restrict__ cursor, int* __restrict__ csr)
{
    const int e = blockIdx.x * 256 + threadIdx.x;
    if (e < NE) {
        const int src = ei[e];
        const int dst = ei[NE + e];
        csr[atomicAdd(&cursor[dst], 1)] = src;
    }
}

// ---------------------------------------------------------------------------
// Gather (XCD-aligned): block j covers a 32-row sub-window of gemm block g
// with g%8 == j%8. Unroll-4 edge loop, bf16 K/H, stats on rounded h.
// ---------------------------------------------------------------------------
#define GATHER_BLOCKS (8 * 49 * 4)   // 1568
__global__ __launch_bounds__(256) void gather_kernel(
    const int* __restrict__ rowst, const int* __restrict__ csr,
    const unsigned short* __restrict__ Kb, const unsigned int* __restrict__ QVp,
    unsigned short* Hb, float* __restrict__ stats)
{
    const int tid = threadIdx.x;
    const int c   = tid & 63;
    const int wv  = tid >> 6;

    const int j     = blockIdx.x;
    const int lane8 = j & 7;
    const int idx   = j >> 3;               // 0..195
    const int g     = lane8 + 8 * (idx >> 2);
    const int sub   = idx & 3;
    const int base  = g * GROWS + sub * 32;

    float s = 0.f, s2 = 0.f;

    for (int t = 0; t < 8; t++) {
        const int n = base + wv + t * 4;
        if (n >= NN) break;
        const unsigned rowoff = (unsigned)(n * DD + c);
        const float k     = bf2f(Kb[rowoff]);
        const float hskip = bf2f(Hb[rowoff]);
        const int e0 = rowst[n], e1 = rowst[n + 1];
        float acc = 0.f;
        int i = e0;
        for (; i + 4 <= e1; i += 4) {
            const int s0 = csr[i], s1 = csr[i + 1], s2i = csr[i + 2], s3 = csr[i + 3];
            const unsigned p0 = QVp[(unsigned)(s0  * DD + c)];
            const unsigned p1 = QVp[(unsigned)(s1  * DD + c)];
            const unsigned p2 = QVp[(unsigned)(s2i * DD + c)];
            const unsigned p3 = QVp[(unsigned)(s3  * DD + c)];
            acc = gate_fma(k, p0, acc);
            acc = gate_fma(k, p1, acc);
            acc = gate_fma(k, p2, acc);
            acc = gate_fma(k, p3, acc);
        }
        for (; i < e1; i++) {
            const unsigned p0 = QVp[(unsigned)(csr[i] * DD + c)];
            acc = gate_fma(k, p0, acc);
        }
        const float o = fmaxf(hskip + acc, 0.f);
        const unsigned short ob = f2bf(o);
        Hb[rowoff] = ob;
        const float orr = bf2f(ob);
        s += orr;
        s2 += orr * orr;
    }

    __shared__ float ls[256], ls2[256];
    ls[tid]  = s;
    ls2[tid] = s2;
    __syncthreads();
    if (tid < 64) {
        const float a = ls[tid]  + ls[tid + 64]  + ls[tid + 128]  + ls[tid + 192];
        const float b = ls2[tid] + ls2[tid + 64] + ls2[tid + 128] + ls2[tid + 192];
        atomicAdd(&stats[c], a);
        atomicAdd(&stats[64 + c], b);
    }
}

// ---------------------------------------------------------------------------
// Pooled segment-sum over bf16 H (batch sorted -> run-length accumulate).
// ---------------------------------------------------------------------------
#define POOL_ROWS 64
__global__ __launch_bounds__(64) void pool_kernel(
    const unsigned short* __restrict__ Hb, const int* __restrict__ batch,
    float* __restrict__ psum, float* __restrict__ pcnt)
{
    const int c  = threadIdx.x;
    const int r0 = blockIdx.x * POOL_ROWS;
    if (r0 >= NN) return;
    const int r1 = min(r0 + POOL_ROWS, NN);

    int cur = batch[r0];
    float acc = 0.f, cnt = 0.f;
    for (int r = r0; r < r1; r++) {
        const int g = batch[r];
        if (g != cur) {
            atomicAdd(&psum[cur * DD + c], acc);
            if (c == 0) atomicAdd(&pcnt[cur], cnt);
            acc = 0.f; cnt = 0.f; cur = g;
        }
        acc += bf2f(Hb[(size_t)r * DD + c]);
        cnt += 1.f;
    }
    atomicAdd(&psum[cur * DD + c], acc);
    if (c == 0) atomicAdd(&pcnt[cur], cnt);
}

// ---------------------------------------------------------------------------
// Final: pooled mean -> folded last-layer BN affine -> logits -> softmax.
// ---------------------------------------------------------------------------
__global__ __launch_bounds__(256) void final_kernel(
    const float* __restrict__ psum, const float* __restrict__ pcnt,
    const float* __restrict__ stats,
    const float* __restrict__ gamma, const float* __restrict__ beta,
    const float* __restrict__ Wlin, const float* __restrict__ blin,
    float* __restrict__ out)
{
    const int g = blockIdx.x * blockDim.x + threadIdx.x;
    if (g >= NG) return;

    const float invc = 1.0f / fmaxf(pcnt[g], 1.0f);
    const float invN = 1.0f / (float)NN;
    float p[DD];
#pragma unroll
    for (int d = 0; d < DD; d++) {
        const float mean = stats[d] * invN;
        const float var  = stats[64 + d] * invN - mean * mean;
        const float inv  = rsqrtf(var + BN_EPS);
        const float a = inv * gamma[d];
        const float b = beta[d] - mean * a;
        p[d] = fmaf(psum[g * DD + d] * invc, a, b);
    }

    float logits[NC];
    float m = -1e30f;
#pragma unroll
    for (int c = 0; c < NC; c++) {
        float acc = blin[c];
#pragma unroll
        for (int d = 0; d < DD; d++) acc = fmaf(p[d], Wlin[d * NC + c], acc);
        logits[c] = acc;
        m = fmaxf(m, acc);
    }
    float sum = 0.f;
#pragma unroll
    for (int c = 0; c < NC; c++) {
        logits[c] = __expf(logits[c] - m);
        sum += logits[c];
    }
    const float inv = 1.f / sum;
#pragma unroll
    for (int c = 0; c < NC; c++) out[g * NC + c] = logits[c] * inv;
}

// ---------------------------------------------------------------------------
extern "C" void kernel_launch(void* const* d_in, const int* in_sizes, int n_in,
                              void* d_out, int out_size, void* d_ws, size_t ws_size,
                              hipStream_t stream)
{
    const float* X     = (const float*)d_in[0];
    const int*   ei    = (const int*)d_in[1];
    const int*   batch = (const int*)d_in[2];
    const float* Wk    = (const float*)d_in[3];
    const float* Wq    = (const float*)d_in[4];
    const float* Wv    = (const float*)d_in[5];
    const float* Ws    = (const float*)d_in[6];
    const float* bk    = (const float*)d_in[7];
    const float* bq    = (const float*)d_in[8];
    const float* bv    = (const float*)d_in[9];
    const float* bconv = (const float*)d_in[10];
    const float* gamma = (const float*)d_in[11];
    const float* beta  = (const float*)d_in[12];
    const float* Wlin  = (const float*)d_in[13];
    const float* blin  = (const float*)d_in[14];
    float* out = (float*)d_out;

    const size_t M = (size_t)NN * DD;
    unsigned short* Kb  = (unsigned short*)d_ws;      // M bf16
    unsigned int*   QVp = (unsigned int*)(Kb + M);    // M packed bf16 q|v
    unsigned short* H0  = (unsigned short*)(QVp + M); // M bf16
    unsigned short* H1  = H0 + M;                     // M bf16
    // --- contiguous zero-init region ---
    int*   deg   = (int*)(H1 + M);                    // NN
    float* psum  = (float*)(deg + NN);                // NG*DD
    float* pcnt  = psum + (size_t)NG * DD;            // NG
    float* stats = pcnt + NG;                         // NL*128
    float* badjX = stats + NL * 128;                  // NL*256 (b.W per layer)
    // --- end zero region ---
    int* rowst  = (int*)(badjX + NL * 256);           // NN+1
    int* cursor = rowst + NN + 1;                     // NN
    int* psums  = cursor + NN;                        // 256
    int* csr    = psums + 256;                        // NE
    bf16x8* whbuf = (bf16x8*)(csr + NE);              // 2048 frags (one layer)
    bf16x8* wlbuf = whbuf + 2048;                     // 2048 frags

    const size_t zero_bytes =
        (size_t)(NN + NG * DD + NG + NL * 128 + NL * 256) * sizeof(float);
    hipMemsetAsync(deg, 0, zero_bytes, stream);

    // ---- layer-0 W fragments (identity fold) ----
    wrefresh_kernel<<<8, 256, 0, stream>>>(
        Wk, Wq, Wv, Ws, nullptr, nullptr, nullptr, whbuf, wlbuf, badjX);

    // ---- CSR build ----
    deg_kernel<<<(NE + 255) / 256, 256, 0, stream>>>(ei, deg);
    scan_partial_kernel<<<NCHUNK, 256, 0, stream>>>(deg, psums);
    scan_offsets_kernel<<<1, 64, 0, stream>>>(psums, rowst);
    scan_final_kernel<<<NCHUNK, 256, 0, stream>>>(deg, psums, rowst, cursor);
    fill_kernel<<<(NE + 255) / 256, 256, 0, stream>>>(ei, cursor, csr);

    // ---- layers ----
    const unsigned short* hin = nullptr;
    for (int l = 0; l < NL; l++) {
        unsigned short* hout = (l & 1) ? H1 : H0;
        if (l == 0) {
            gemm0_mfma<<<GEMM_BLOCKS, 256, 0, stream>>>(
                X, whbuf, wlbuf, bk, bq, bv, bconv, badjX, Kb, QVp, hout);
        } else {
            wrefresh_kernel<<<8, 256, 0, stream>>>(
                Wk + l * 4096, Wq + l * 4096, Wv + l * 4096, Ws + l * 4096,
                stats + (l - 1) * 128, gamma + (l - 1) * 64, beta + (l - 1) * 64,
                whbuf, wlbuf, badjX + l * 256);
            gemmb_mfma<<<GEMM_BLOCKS, 256, 0, stream>>>(
                hin, whbuf, wlbuf,
                bk + l * 64, bq + l * 64, bv + l * 64, bconv + l * 64,
                badjX + l * 256, Kb, QVp, hout);
        }
        gather_kernel<<<GATHER_BLOCKS, 256, 0, stream>>>(
            rowst, csr, Kb, QVp, hout, stats + l * 128);
        hin = hout;
    }

    pool_kernel<<<(NN + POOL_ROWS - 1) / POOL_ROWS, 64, 0, stream>>>(
        hin, batch, psum, pcnt);
    final_kernel<<<1, 256, 0, stream>>>(
        psum, pcnt, stats + 4 * 128, gamma + 4 * 64, beta + 4 * 64, Wlin, blin, out);
}